// Round 1
// baseline (393.961 us; speedup 1.0000x reference)
//
#include <hip/hip_runtime.h>
#include <math.h>

// Problem constants (x: [4, 64, 384, 384] fp32)
#define QLS_T   256            // B*C = 4*64, sequential scan axis
#define QLS_HW  (384 * 384)    // independent spatial locations

// Quantizer constants from the reference
#define Q_SCALE      16.0f
#define INV_Q_SCALE  (1.0f / 16.0f)
#define QMAXF        7.9375f
#define QMINF        (-8.0f)
#define LUT_IN_SCALE 4096.0f
#define INV_LUT_IN   (1.0f / 4096.0f)
#define LUT_IN_MAX   32767.0f
#define LUT_OUT      65536.0f
#define INV_LUT_OUT  (1.0f / 65536.0f)

// One thread per spatial location. 147456 threads = 2304 blocks x 64
// = exactly 9 waves/CU on 256 CUs (perfect balance, single-wave blocks).
__global__ __launch_bounds__(64) void QuantizedLogSoftmax_12970801234623_kernel(
    const float* __restrict__ x, float* __restrict__ out) {
    const int i = blockIdx.x * 64 + threadIdx.x;   // spatial index in [0, HW)
    const float* xp = x + i;

    // Sequential quantized log-sum-exp scan over the 256 planes.
    // All grid ops (floor, min, /4096, max, clip) are bit-exact fp32;
    // log1pf/expf (ocml, ~1ulp) match numpy to within one 1/65536 LUT step,
    // and the scan map is contractive in s, so drift stays << 1/16.
    float s = QMINF;
    #pragma unroll 8
    for (int t = 0; t < QLS_T; ++t) {
        float v = xp[t * QLS_HW];                       // coalesced: lane i -> addr i
        float diff = fabsf(s - v);
        float d_int = fminf(floorf(diff * LUT_IN_SCALE), LUT_IN_MAX);
        float d_q = d_int * INV_LUT_IN;                 // exact (d_int < 2^24, /2^12)
        float lu = rintf(log1pf(expf(-d_q)) * LUT_OUT) * INV_LUT_OUT;
        s = fmaxf(s, v) + lu;                           // max(sum_exp, t) + lu
        s = fminf(fmaxf(s, QMINF), QMAXF);              // clip(s, QMIN, QMAX)
    }

    // Output pass: re-read x (L3-resident), quantize to 1/16 grid.
    // Non-temporal stores keep x planes from being evicted from L3.
    float* op = out + i;
    #pragma unroll 4
    for (int t = 0; t < QLS_T; ++t) {
        float v = xp[t * QLS_HW];
        float q = fminf(fmaxf(rintf((v - s) * Q_SCALE), -128.0f), 127.0f);
        __builtin_nontemporal_store(q * INV_Q_SCALE, op + t * QLS_HW);
    }
}

extern "C" void kernel_launch(void* const* d_in, const int* in_sizes, int n_in,
                              void* d_out, int out_size, void* d_ws, size_t ws_size,
                              hipStream_t stream) {
    const float* x = (const float*)d_in[0];
    float* out = (float*)d_out;
    // 147456 spatial locations, one thread each.
    const int threads = 64;
    const int blocks = QLS_HW / threads;  // 2304
    QuantizedLogSoftmax_12970801234623_kernel<<<blocks, threads, 0, stream>>>(x, out);
}

// Round 2
// 269.258 us; speedup vs baseline: 1.4631x; 1.4631x over previous
//
#include <hip/hip_runtime.h>
#include <math.h>

// Problem constants (x: [4, 64, 384, 384] fp32)
#define QLS_T   256            // B*C = 4*64, sequential scan axis
#define QLS_HW  (384 * 384)    // independent spatial locations

// Quantizer constants from the reference
#define Q_SCALE      16.0f
#define INV_Q_SCALE  (1.0f / 16.0f)
#define QMAXF        7.9375f
#define QMINF        (-8.0f)
#define LUT_IN_SCALE 4096.0f
#define LUT_IN_MAX   32767.0f
#define INV_LUT_OUT  (1.0f / 65536.0f)

// log1p(exp(-d)) = log2(1 + 2^(-d*log2e)) * ln2, on raw v_exp_f32/v_log_f32.
//   NEG_LOG2E_DIV:   -log2(e)/4096  (applied directly to d_int)
//   LN2_X_65536:      ln(2)*65536   (fold the *65536 LUT-grid scale into the log)
#define NEG_LOG2E_DIV (-1.4426950408889634f / 4096.0f)
#define LN2_X_65536   45426.09375f

// One thread per spatial location. 147456 threads = 2304 blocks x 64
// = exactly 9 waves/CU on 256 CUs (perfect balance, single-wave blocks).
//
// R1 post-mortem: ocml expf+log1pf cost ~150 VALU instrs/step -> VALU-bound
// at 232 us (VALUBusy 62%, HBM 16%). This round: hardware exp2/log2 only
// (~12 instrs/step) -> HBM-bound. Error in lu*65536 before rint is ~±0.01;
// rounding flips are 1/65536 each and the scan is contractive, so drift
// stays far below the 1/16 output grid.
__global__ __launch_bounds__(64) void QuantizedLogSoftmax_12970801234623_kernel(
    const float* __restrict__ x, float* __restrict__ out) {
    const int i = blockIdx.x * 64 + threadIdx.x;   // spatial index in [0, HW)
    const float* xp = x + i;

    float s = QMINF;
    #pragma unroll 8
    for (int t = 0; t < QLS_T; ++t) {
        float v = xp[t * QLS_HW];                       // coalesced: lane i -> addr i
        float diff = fabsf(s - v);
        // d_int = min(floor(diff*4096), 32767); d_q = d_int/4096 (exact grid)
        float d_int = fminf(floorf(diff * LUT_IN_SCALE), LUT_IN_MAX);
        // lu = round(log1p(exp(-d_q))*65536)/65536 via v_exp_f32 + v_log_f32
        float e  = __builtin_amdgcn_exp2f(d_int * NEG_LOG2E_DIV);
        float lu = rintf(__builtin_amdgcn_logf(1.0f + e) * LN2_X_65536) * INV_LUT_OUT;
        s = fmaxf(s, v) + lu;                           // max(sum_exp, t) + lu
        s = fminf(fmaxf(s, QMINF), QMAXF);              // clip(s, QMIN, QMAX)
    }

    // Output pass: re-read x (L3-resident, FETCH_SIZE confirms single HBM read),
    // quantize to 1/16 grid. Non-temporal stores: out is never re-read.
    float* op = out + i;
    #pragma unroll 4
    for (int t = 0; t < QLS_T; ++t) {
        float v = xp[t * QLS_HW];
        float q = fminf(fmaxf(rintf((v - s) * Q_SCALE), -128.0f), 127.0f);
        __builtin_nontemporal_store(q * INV_Q_SCALE, op + t * QLS_HW);
    }
}

extern "C" void kernel_launch(void* const* d_in, const int* in_sizes, int n_in,
                              void* d_out, int out_size, void* d_ws, size_t ws_size,
                              hipStream_t stream) {
    const float* x = (const float*)d_in[0];
    float* out = (float*)d_out;
    const int threads = 64;
    const int blocks = QLS_HW / threads;  // 2304
    QuantizedLogSoftmax_12970801234623_kernel<<<blocks, threads, 0, stream>>>(x, out);
}